// Round 4
// baseline (147.616 us; speedup 1.0000x reference)
//
#include <hip/hip_runtime.h>
#include <math.h>

#define Bn 8
#define Qn 20
#define Pn 12
#define Nn 4096
#define Gn 2048
#define Mn 1280   /* Q*FACTOR */
#define Fn 64
#define KNB 7     /* K_NEIGHBORS - 1 */
#define SA 8      /* gt splits for chamfer A (2048/256)  */
#define SB 5      /* recon splits for chamfer B (1280/256) */
#define DONE_TARGET 152  /* 8 hungarian + 40 repulsion + 104 chamfer reducers */

// ---------------- workspace layout (32-bit words) ----------------
// cham  : 0      (1920)  (B,Q,P)
// ns    : 1920   (1920)
// dd    : 3840   (1920)
// cost  : 5760   (1920)
// cnt   : 7680   (96)
// acc   : 7776   (6)     0 cls, 1 param, 2 pvd, 3 rep, 4 ch1, 5 ch2
// costc : 7784   (8)     per-batch cost-block counters (target 20)
// chamAc: 7792   (40)    per-A-chunk counters (target SA)
// chamBc: 7832   (64)    per-B-chunk counters (target SB)
// done  : 7896   (1)     global contributor counter (target 152)
// mA1u  : 8192   (10240) per-point running min, float bits as uint
// mA2u  : 18432  (10240)
// mB1u  : 28672  (16384)
// mB2u  : 45056  (16384) .. 61440

// Cross-block data discipline (single dispatch, cross-XCD): all communicated
// values move via atomic RMWs (resolve at the device coherence point) with
// __threadfence() for ordering — the primitive class proven intra-dispatch in R3.
__device__ __forceinline__ float aread(float* p) { return atomicAdd(p, 0.0f); }
__device__ __forceinline__ void awrite(float* p, float v) { atomicExch(p, v); }
__device__ __forceinline__ unsigned int auread(unsigned int* p) { return atomicAdd(p, 0u); }

__device__ __forceinline__ void contribute(float* acc, int* done, float* out) {
    __threadfence();
    int old = atomicAdd(done, 1);
    if (old == DONE_TARGET - 1) {
        __threadfence();
        float a0 = aread(&acc[0]);
        float a1 = aread(&acc[1]);
        float a2 = aread(&acc[2]);
        float a3 = aread(&acc[3]);
        float a4 = aread(&acc[4]);
        float a5 = aread(&acc[5]);
        out[0] = a0 + 0.5f * a1 + 20.f * a2 + a3 + a4 + a5;
    }
}

// Zero counters/acc; set chamfer min slots to +INF bits (poison 0xAA would also
// order above +INF as uint, but we do NOT rely on the poison pattern).
__global__ void init_kernel(unsigned int* wsu) {
    int tid = blockIdx.x * 256 + threadIdx.x;
    for (int k = tid; k < 160; k += 64 * 256) wsu[7776 + k] = 0u;
    for (int k = tid; k < 53248; k += 64 * 256) wsu[8192 + k] = 0x7F800000u;
}

// ============ mega: cost(160) + repulsion(40) + chamfer(640), with promotions ============
__global__ void mega_kernel(const float* __restrict__ pred_logits,
                            const float* __restrict__ pred_normals,
                            const float* __restrict__ pred_distances,
                            const float* __restrict__ gt_normals,
                            const float* __restrict__ gt_distances,
                            const float* __restrict__ points,
                            const int*   __restrict__ gt_masks,
                            const float* __restrict__ recon,
                            const float* __restrict__ gt,
                            float* __restrict__ ws, float* __restrict__ out) {
    __shared__ float smem[2 * Pn * 256];
    __shared__ double hsm[Pn * Qn];
    __shared__ int sflag;
    const int blk = blockIdx.x;
    const int tid = threadIdx.x;

    float* cham = ws;
    float* ns   = ws + 1920;
    float* dd   = ws + 3840;
    float* cost = ws + 5760;
    float* cnt  = ws + 7680;
    float* acc  = ws + 7776;
    int*   costc  = (int*)(ws + 7784);
    int*   chamAc = (int*)(ws + 7792);
    int*   chamBc = (int*)(ws + 7832);
    int*   done   = (int*)(ws + 7896);
    unsigned int* mA1u = (unsigned int*)(ws + 8192);
    unsigned int* mA2u = (unsigned int*)(ws + 18432);
    unsigned int* mB1u = (unsigned int*)(ws + 28672);
    unsigned int* mB2u = (unsigned int*)(ws + 45056);

    if (blk < 160) {
        // ---------------- cost path: one block per (b,q) ----------------
        const int b = blk / Qn, q = blk % Qn;
        const float nx = pred_normals[(b * Qn + q) * 3 + 0];
        const float ny = pred_normals[(b * Qn + q) * 3 + 1];
        const float nz = pred_normals[(b * Qn + q) * 3 + 2];
        const float dq = pred_distances[b * Qn + q];

        float accs[Pn], accw[Pn];
#pragma unroll
        for (int p = 0; p < Pn; ++p) { accs[p] = 0.f; accw[p] = 0.f; }

        const float* ptb = points + (size_t)b * Nn * 3;
        const int*   mb  = gt_masks + (size_t)b * Pn * Nn;

        for (int n = tid; n < Nn; n += 256) {
            float px = ptb[n * 3 + 0], py = ptb[n * 3 + 1], pz = ptb[n * 3 + 2];
            float pp = fabsf(px * nx + py * ny + pz * nz - dq);
#pragma unroll
            for (int p = 0; p < Pn; ++p) {
                float m = (float)mb[(size_t)p * Nn + n];
                accs[p] += pp * m;
                accw[p] += m;
            }
        }
#pragma unroll
        for (int p = 0; p < Pn; ++p) {
            smem[p * 256 + tid] = accs[p];
            smem[(p + Pn) * 256 + tid] = accw[p];
        }
        __syncthreads();
        for (int off = 128; off > 0; off >>= 1) {
            if (tid < off) {
#pragma unroll
                for (int r = 0; r < 2 * Pn; ++r) smem[r * 256 + tid] += smem[r * 256 + tid + off];
            }
            __syncthreads();
        }
        if (tid < Pn) {
            const int p = tid;
            float c  = smem[(p + Pn) * 256];
            float cv = smem[p * 256] / fmaxf(c, 1.f);
            float gnx = gt_normals[(b * Pn + p) * 3 + 0];
            float gny = gt_normals[(b * Pn + p) * 3 + 1];
            float gnz = gt_normals[(b * Pn + p) * 3 + 2];
            float nsim = 1.f - fabsf(nx * gnx + ny * gny + nz * gnz);
            float ddv  = fabsf(dq - gt_distances[b * Pn + p]);
            int idx = (b * Qn + q) * Pn + p;
            awrite(&cham[idx], cv);
            awrite(&ns[idx],   nsim);
            awrite(&dd[idx],   ddv);
            awrite(&cost[idx], nsim + 0.5f * ddv + 5.f * ((c > 0.f) ? cv : 1.f));
            if (q == 0) awrite(&cnt[b * Pn + p], c);
        }
        __syncthreads();
        if (tid == 0) {
            __threadfence();
            int old = atomicAdd(&costc[b], 1);
            sflag = (old == Qn - 1) ? 1 : 0;
        }
        __syncthreads();
        if (!sflag) return;
        if (tid >= 64) return;
        __threadfence();

        // ---- promoted: wave-parallel transposed rectangular JV for batch b ----
        // (identical algorithm to R2/R3 — proven absmax 0.0; pad-to-square equivalent)
        const int t = tid;
        for (int k = t; k < Qn * Pn; k += 64)
            hsm[(k % Pn) * Qn + (k / Pn)] = (double)aread(&cost[b * Qn * Pn + k]);
        // wave-synchronous LDS: compiler inserts lgkmcnt before dependent ds_read

        const int col = t;
        const bool isCol = (col >= 1 && col <= Qn);
        double v = 0.0, u = 0.0, minv = 0.0;
        int way = 0, p = 0;

        for (int i = 1; i <= Pn; ++i) {
            const int p0 = i;
            minv = 1e18;
            bool used = false;
            bool rowInPath = false;
            int j0 = 0;
            while (true) {
                if (col == j0) used = true;
                int i0 = (j0 == 0) ? p0 : __shfl(p, j0);
                if (t == i0) rowInPath = true;
                double u_i0 = __shfl(u, i0);
                double mv = 1e18;
                if (isCol && !used) {
                    double cur = hsm[(i0 - 1) * Qn + (col - 1)] - u_i0 - v;
                    if (cur < minv) { minv = cur; way = j0; }
                    mv = minv;
                }
                double bv = mv; int bj = col;
#pragma unroll
                for (int off = 16; off > 0; off >>= 1) {
                    double ov = __shfl_down(bv, off);
                    int    oj = __shfl_down(bj, off);
                    if (ov < bv) { bv = ov; bj = oj; }
                }
                double delta = __shfl(bv, 0);
                int    j1    = __shfl(bj, 0);
                if (used || col == 0) v -= delta;
                else if (isCol)       minv -= delta;
                if (rowInPath)        u += delta;
                j0 = j1;
                int pj0 = __shfl(p, j0);
                if (pj0 == 0) break;
            }
            while (j0 != 0) {
                int wj = __shfl(way, j0);
                int pw = (wj == 0) ? p0 : __shfl(p, wj);
                if (col == j0) p = pw;
                j0 = wj;
            }
        }

        // ---- fused small losses for batch b ----
        float cls = 0.f, par = 0.f, pvd = 0.f;
        if (isCol) {
            float x = pred_logits[b * Qn + (col - 1)];
            float tgt = (p > 0) ? 1.f : 0.f;
            cls = fmaxf(x, 0.f) - x * tgt + log1pf(expf(-fabsf(x)));
            if (p > 0) {
                int idx = (b * Qn + (col - 1)) * Pn + (p - 1);
                par = aread(&ns[idx]) + aread(&dd[idx]);
                pvd = (aread(&cnt[b * Pn + (p - 1)]) > 0.f) ? aread(&cham[idx]) : 0.f;
            }
        }
        for (int off = 32; off > 0; off >>= 1) {
            cls += __shfl_down(cls, off);
            par += __shfl_down(par, off);
            pvd += __shfl_down(pvd, off);
        }
        if (t == 0) {
            atomicAdd(&acc[0], cls / (float)(Bn * Qn));
            atomicAdd(&acc[1], par / (float)(Bn * Pn));
            atomicAdd(&acc[2], pvd / (float)(Bn * Pn));
            contribute(acc, done, out);
        }
    } else if (blk < 200) {
        // ---------------- repulsion: 4 waves per block, one 64-pt group per wave ----------------
        const int wave = tid >> 6, lane = tid & 63;
        const int g = (blk - 160) * 4 + wave;
        float* xs = smem + wave * 192;
        float* ys = xs + 64;
        float* zs = xs + 128;
        const float* base = recon + (size_t)g * Fn * 3;
        xs[lane] = base[lane * 3 + 0];
        ys[lane] = base[lane * 3 + 1];
        zs[lane] = base[lane * 3 + 2];
        // wave-local LDS (no cross-wave sharing yet)
        float best[KNB];
#pragma unroll
        for (int k = 0; k < KNB; ++k) best[k] = 3.4e38f;
        const float xi = xs[lane], yi = ys[lane], zi = zs[lane];
        for (int j = 0; j < Fn; ++j) {
            if (j == lane) continue;
            float dx = xi - xs[j], dy = yi - ys[j], dz = zi - zs[j];
            float d2 = dx * dx + dy * dy + dz * dz;
            if (d2 < best[KNB - 1]) {
                int k = KNB - 1;
                while (k > 0 && best[k - 1] > d2) { best[k] = best[k - 1]; --k; }
                best[k] = d2;
            }
        }
        float sum = 0.f;
#pragma unroll
        for (int k = 0; k < KNB; ++k) {
            float dn = fmaxf(best[k], 1e-12f);
            float w  = expf(-dn / (0.03f * 0.03f));
            sum += (0.07f - sqrtf(dn)) * w;
        }
        for (int off = 32; off > 0; off >>= 1) sum += __shfl_down(sum, off);
        if (lane == 0) smem[1000 + wave] = fmaxf(sum / (float)(Fn * KNB), 0.f);
        __syncthreads();
        if (tid == 0) {
            float total = (smem[1000] + smem[1001] + smem[1002] + smem[1003]) / (float)(Bn * Qn);
            atomicAdd(&acc[3], total);
            contribute(acc, done, out);
        }
    } else {
        // ---------------- chamfer: one block per (direction, outer-chunk, split) ----------------
        int a = blk - 200;
        const bool isA = (a < 320);
        int ob, s, idx;
        float x, y, z;
        const float* inner;
        unsigned int *mu1, *mu2;
        int* ctr; int target;
        if (isA) {
            ob = a / SA; s = a % SA;
            idx = ob * 256 + tid;                 // over B*M
            int b = idx / Mn;
            x = recon[idx * 3 + 0]; y = recon[idx * 3 + 1]; z = recon[idx * 3 + 2];
            inner = gt + ((size_t)b * Gn + s * 256) * 3;
            mu1 = mA1u; mu2 = mA2u; ctr = &chamAc[ob]; target = SA;
        } else {
            a -= 320;
            ob = a / SB; s = a % SB;
            idx = ob * 256 + tid;                 // over B*G
            int b = idx / Gn;
            x = gt[idx * 3 + 0]; y = gt[idx * 3 + 1]; z = gt[idx * 3 + 2];
            inner = recon + ((size_t)b * Mn + s * 256) * 3;
            mu1 = mB1u; mu2 = mB2u; ctr = &chamBc[ob]; target = SB;
        }
        float* tx = smem;
        float* ty = smem + 256;
        float* tz = smem + 512;
        tx[tid] = inner[tid * 3 + 0];
        ty[tid] = inner[tid * 3 + 1];
        tz[tid] = inner[tid * 3 + 2];
        __syncthreads();
        float m1 = 3.4e38f, m2 = 3.4e38f;
        for (int j = 0; j < 256; ++j) {
            float dx = x - tx[j], dy = y - ty[j], dz = z - tz[j];
            float d1 = fabsf(dx) + fabsf(dy) + fabsf(dz);
            float d2 = dx * dx + dy * dy + dz * dz;
            m1 = fminf(m1, d1); m2 = fminf(m2, d2);
        }
        // fold this split into the per-point running min (d>=0 => float bits uint-ordered)
        atomicMin(&mu1[idx], __float_as_uint(m1));
        atomicMin(&mu2[idx], __float_as_uint(m2));
        __syncthreads();
        if (tid == 0) {
            __threadfence();
            int old = atomicAdd(ctr, 1);
            sflag = (old == target - 1) ? 1 : 0;
        }
        __syncthreads();
        if (!sflag) return;
        __threadfence();
        // ---- promoted: reduce this outer chunk's 256 final mins ----
        float scale = isA ? (0.5f / (float)(Bn * Mn)) : (0.5f / (float)(Bn * Gn));
        float c1 = __uint_as_float(auread(&mu1[idx])) * scale;
        float c2 = __uint_as_float(auread(&mu2[idx])) * scale;
        float* s1 = smem;
        float* s2 = smem + 256;
        __syncthreads();
        s1[tid] = c1; s2[tid] = c2;
        __syncthreads();
        for (int off = 128; off > 0; off >>= 1) {
            if (tid < off) { s1[tid] += s1[tid + off]; s2[tid] += s2[tid + off]; }
            __syncthreads();
        }
        if (tid == 0) {
            atomicAdd(&acc[4], s1[0]);
            atomicAdd(&acc[5], s2[0]);
            contribute(acc, done, out);
        }
    }
}

extern "C" void kernel_launch(void* const* d_in, const int* in_sizes, int n_in,
                              void* d_out, int out_size, void* d_ws, size_t ws_size,
                              hipStream_t stream) {
    const float* pred_logits    = (const float*)d_in[0];
    const float* pred_normals   = (const float*)d_in[1];
    const float* pred_distances = (const float*)d_in[2];
    const float* gt_normals     = (const float*)d_in[3];
    const float* gt_distances   = (const float*)d_in[4];
    const int*   gt_masks       = (const int*)d_in[5];
    const float* points         = (const float*)d_in[6];
    const float* recon          = (const float*)d_in[7];
    const float* gt             = (const float*)d_in[8];
    // d_in[9] (gt_index) is unused by the reference.

    init_kernel<<<64, 256, 0, stream>>>((unsigned int*)d_ws);
    mega_kernel<<<840, 256, 0, stream>>>(pred_logits, pred_normals, pred_distances,
                                         gt_normals, gt_distances, points, gt_masks,
                                         recon, gt, (float*)d_ws, (float*)d_out);
}